// Round 4
// baseline (21976.556 us; speedup 1.0000x reference)
//
#include <hip/hip_runtime.h>

// XTAttention — ROUND 3: dtype-dual naive probe. The round-2 naive kernel
// NaN'd => inputs are almost certainly f32, not bf16 (f32 read as bf16 =>
// random-exponent garbage => NaN). This round detects dtype ON DEVICE and
// handles both, keeping the audited-naive structure. Intermediates f32 in ws.
// B=128, N=128, D=1024, H=8, HD=128. Einsums are UNtransposed matmuls.

typedef unsigned short u16;

__device__ __forceinline__ float bf2f(u16 x) {
  union { unsigned u; float f; } v;
  v.u = ((unsigned)x) << 16;
  return v.f;
}

__device__ __forceinline__ u16 f2bf(float f) {
  union { float f; unsigned u; } v;
  v.f = f;
  unsigned r = v.u + 0x7fffu + ((v.u >> 16) & 1u);  // RTNE
  return (u16)(r >> 16);
}

// Load element i of tensor p under runtime dtype flag (1 = f32, 0 = bf16).
__device__ __forceinline__ float ldv(const void* p, size_t i, int f32) {
  return f32 ? ((const float*)p)[i] : bf2f(((const u16*)p)[i]);
}

// ---------------------------------------------------------------------------
// Dtype detection: sample even-index u16s of `words`. If data is bf16, these
// are real bf16 values (sane exponents ~100%). If f32, these are mantissa
// halves (uniform random => ~19% sane). Writes flag: 1 = f32, 0 = bf16.
// ---------------------------------------------------------------------------
__global__ void detect_dtype(const void* words, int* flag) {
  __shared__ int cnt;
  if (threadIdx.x == 0) cnt = 0;
  __syncthreads();
  const u16* w = (const u16*)words;
  int local = 0;
  for (int i = threadIdx.x; i < 2048; i += 256) {
    const u16 v = w[2 * i];
    const int e = (v >> 7) & 0xFF;
    if (v == 0 || (e >= 0x60 && e <= 0x8F)) local++;
  }
  atomicAdd(&cnt, local);
  __syncthreads();
  if (threadIdx.x == 0) *flag = (cnt >= 1434) ? 0 : 1;  // >=70% sane => bf16
}

// ---------------------------------------------------------------------------
// 7 projections, simple 16x16 LDS-tiled GEMM, f32 accumulate, f32 out (ws).
// C[p][ml][n] = sum_k A[b0*128+ml][k] * W[p][k][n]
// ---------------------------------------------------------------------------
__global__ __launch_bounds__(256) void proj_simple(
    const void* __restrict__ words, const void* __restrict__ position,
    const void* __restrict__ conscious,
    const void* w0, const void* w1, const void* w2, const void* w3,
    const void* w4, const void* w5, const void* w6,
    float* __restrict__ P, int b0, int chb, const int* __restrict__ flag) {
  __shared__ float As[16][17];
  __shared__ float Bs[16][17];
  const int f32 = *flag;
  const int p = blockIdx.z;
  const void* A = (p < 3) ? words : ((p < 5) ? position : conscious);
  const void* W;
  switch (p) {
    case 0: W = w0; break; case 1: W = w1; break; case 2: W = w2; break;
    case 3: W = w3; break; case 4: W = w4; break; case 5: W = w5; break;
    default: W = w6; break;
  }
  float* C = P + (size_t)p * (size_t)chb * 131072ull;
  const int tx = threadIdx.x, ty = threadIdx.y;
  const int n = blockIdx.x * 16 + tx;
  const int ml = blockIdx.y * 16 + ty;   // local C row
  const int mg = b0 * 128 + ml;          // global A row
  float acc = 0.f;
  for (int kt = 0; kt < 1024; kt += 16) {
    As[ty][tx] = ldv(A, (size_t)mg * 1024 + kt + tx, f32);
    Bs[ty][tx] = ldv(W, (size_t)(kt + ty) * 1024 + n, f32);
    __syncthreads();
    #pragma unroll
    for (int kk = 0; kk < 16; ++kk) acc += As[ty][kk] * Bs[kk][tx];
    __syncthreads();
  }
  C[(size_t)ml * 1024 + n] = acc;
}

// ---------------------------------------------------------------------------
// Attention, naive: one block (256 threads) per (b_local, h). P/merged f32.
// sim[i][d] = (sum_j qw[i][hj]*kw[j][hd] + qp*kp + qc*kc) * SCALE
// softmax over d per row i; merged[b,i,h*128+d] = sum_j attn[i][j]*vw[j][hd].
// ---------------------------------------------------------------------------
__global__ __launch_bounds__(256) void attn_simple(
    const float* __restrict__ P, int chb, float* __restrict__ merged) {
  __shared__ float sim[128][128];  // 64 KB
  const int h = blockIdx.x, b = blockIdx.y;  // b chunk-local
  const int tid = threadIdx.x;
  const size_t MS = (size_t)chb * 131072ull;
  const float* qw = P + 0 * MS; const float* kw = P + 1 * MS;
  const float* vw = P + 2 * MS; const float* qp = P + 3 * MS;
  const float* kp = P + 4 * MS; const float* qc = P + 5 * MS;
  const float* kc = P + 6 * MS;
  const size_t rb = (size_t)b * 128;
  const int hc = h * 128;

  for (int e = tid; e < 16384; e += 256) {
    const int i = e >> 7, d = e & 127;
    float acc = 0.f;
    for (int j = 0; j < 128; ++j) {
      acc += qw[(rb + i) * 1024 + hc + j] * kw[(rb + j) * 1024 + hc + d];
      acc += qp[(rb + i) * 1024 + hc + j] * kp[(rb + j) * 1024 + hc + d];
      acc += qc[(rb + i) * 1024 + hc + j] * kc[(rb + j) * 1024 + hc + d];
    }
    sim[i][d] = acc * 0.08838834764831845f;  // * HD^-0.5
  }
  __syncthreads();

  if (tid < 128) {
    float mx = -3.0e38f;
    for (int d = 0; d < 128; ++d) mx = fmaxf(mx, sim[tid][d]);
    float s = 0.f;
    for (int d = 0; d < 128; ++d) {
      const float e = __expf(sim[tid][d] - mx);
      sim[tid][d] = e;
      s += e;
    }
    const float inv = 1.f / s;
    for (int d = 0; d < 128; ++d) sim[tid][d] *= inv;
  }
  __syncthreads();

  for (int e = tid; e < 16384; e += 256) {
    const int i = e >> 7, d = e & 127;
    float acc = 0.f;
    for (int j = 0; j < 128; ++j)
      acc += sim[i][j] * vw[(rb + j) * 1024 + hc + d];
    merged[(rb + i) * 1024 + hc + d] = acc;  // [b_local, i, h*128+d]
  }
}

// ---------------------------------------------------------------------------
// Final projection: out = merged @ Wo + bo; output dtype follows flag.
// ---------------------------------------------------------------------------
__global__ __launch_bounds__(256) void final_simple(
    const float* __restrict__ A, const void* __restrict__ W,
    const void* __restrict__ bias, void* __restrict__ out, int b0,
    const int* __restrict__ flag) {
  __shared__ float As[16][17];
  __shared__ float Bs[16][17];
  const int f32 = *flag;
  const int tx = threadIdx.x, ty = threadIdx.y;
  const int n = blockIdx.x * 16 + tx;
  const int ml = blockIdx.y * 16 + ty;
  float acc = 0.f;
  for (int kt = 0; kt < 1024; kt += 16) {
    As[ty][tx] = A[(size_t)ml * 1024 + kt + tx];
    Bs[ty][tx] = ldv(W, (size_t)(kt + ty) * 1024 + n, f32);
    __syncthreads();
    #pragma unroll
    for (int kk = 0; kk < 16; ++kk) acc += As[ty][kk] * Bs[kk][tx];
    __syncthreads();
  }
  const float r = acc + ldv(bias, n, f32);
  const size_t g = (size_t)(b0 * 128 + ml) * 1024 + n;
  if (f32) ((float*)out)[g] = r;
  else ((u16*)out)[g] = f2bf(r);
}

// ---------------------------------------------------------------------------
extern "C" void kernel_launch(void* const* d_in, const int* in_sizes, int n_in,
                              void* d_out, int out_size, void* d_ws, size_t ws_size,
                              hipStream_t stream) {
  // d_in: 0 words, 1 position, 2 conscious, 3 Wq_w, 4 Wk_w, 5 Wv_w,
  //       6 Wq_p, 7 Wk_p, 8 Wq_c, 9 Wk_c, 10 Wo, 11 bo
  // ws layout: [flag int, 64B pad][P: 7*CHB*131072 f32][merged: CHB*131072 f32]
  int CHB = 128;
  while (CHB > 1 && 64ull + 8ull * (size_t)CHB * 131072ull * 4ull > ws_size)
    CHB >>= 1;

  int* flag = (int*)d_ws;
  float* P = (float*)((char*)d_ws + 64);
  float* merged = P + 7ull * (size_t)CHB * 131072ull;

  detect_dtype<<<1, 256, 0, stream>>>(d_in[0], flag);

  for (int b0 = 0; b0 < 128; b0 += CHB) {
    proj_simple<<<dim3(64, CHB * 8, 7), dim3(16, 16), 0, stream>>>(
        d_in[0], d_in[1], d_in[2],
        d_in[3], d_in[4], d_in[5], d_in[6], d_in[7], d_in[8], d_in[9],
        P, b0, CHB, flag);
    attn_simple<<<dim3(8, CHB), 256, 0, stream>>>(P, CHB, merged);
    final_simple<<<dim3(64, CHB * 8), dim3(16, 16), 0, stream>>>(
        merged, d_in[10], d_in[11], d_out, b0, flag);
  }
}